// Round 16
// baseline (249.814 us; speedup 1.0000x reference)
//
#include <hip/hip_runtime.h>
#include <hip/hip_bf16.h>
#include <math.h>

#define NN 65536          // nodes
#define NE 196608         // edges (without self loops)
#define ET (NE + NN)      // edges + self loops = 262144
#define NG 2048           // graphs
#define FIN 9
#define DD 128
#define H1 10
#define KK (H1 * DD)      // 1280
#define LRS 0.2f
#define XSB 36            // xsb row stride (ushorts): 72B rows

typedef __attribute__((ext_vector_type(8))) short short8v;
typedef __attribute__((ext_vector_type(4))) float f32x4;

__device__ __forceinline__ float lrelu(float v) { return v >= 0.f ? v : LRS * v; }
__device__ __forceinline__ float eluf(float v)  { return v > 0.f ? v : expm1f(v); }

// float -> bf16 round-to-nearest-even (3 int ops, no libcall)
__device__ __forceinline__ unsigned short f2bf(float f) {
    unsigned int u = __float_as_uint(f);
    u += 0x7FFFu + ((u >> 16) & 1u);
    return (unsigned short)(u >> 16);
}
__device__ __forceinline__ float bf2f(unsigned short s) {
    return __uint_as_float((unsigned int)s << 16);
}

// ---- setup: packW2 | alpha1+prep | gptr | packW1pT | count (deg pre-zeroed
// ---- by hipMemsetAsync). All branches independent. -------------------------
__global__ __launch_bounds__(256) void setup_kernel(
        const float* __restrict__ W1, const float* __restrict__ W2,
        const float* __restrict__ a_src1, const float* __restrict__ a_dst1,
        const float* __restrict__ x, const int* __restrict__ batch,
        const int* __restrict__ ei,
        unsigned short* __restrict__ W2p, unsigned short* __restrict__ W1pT,
        float* __restrict__ as1, float* __restrict__ ad1,
        int* __restrict__ deg, int* __restrict__ gptr) {
    __shared__ float ws_s[FIN * H1], wd_s[FIN * H1];
    const int b = blockIdx.x;
    const int t = threadIdx.x;
    if (b < 640) {
        // W2 (1280x128 fp32) -> bf16 B-fragment layout
        int idx = b * 256 + t;
        int r  = idx & 7;
        int l  = (idx >> 3) & 63;
        int nt = (idx >> 9) & 7;
        int kt = idx >> 12;
        int k = kt * 32 + ((l >> 4) << 3) + r;
        int n = nt * 16 + (l & 15);
        W2p[idx] = f2bf(W2[(size_t)k * DD + n]);
    } else if (b < 896) {
        if (t < FIN * H1) {
            int f = t / H1, h = t - f * H1;
            float s = 0.f, d = 0.f;
            for (int c = 0; c < DD; ++c) {
                float w = W1[f * KK + h * DD + c];
                s = fmaf(w, a_src1[h * DD + c], s);
                d = fmaf(w, a_dst1[h * DD + c], d);
            }
            ws_s[t] = s;
            wd_s[t] = d;
        }
        __syncthreads();
        int n = (b - 640) * 256 + t;
        float xv[FIN];
#pragma unroll
        for (int f = 0; f < FIN; ++f) xv[f] = x[(size_t)n * FIN + f];
#pragma unroll
        for (int h = 0; h < H1; ++h) {
            float s = 0.f, d = 0.f;
#pragma unroll
            for (int f = 0; f < FIN; ++f) {
                s = fmaf(xv[f], ws_s[f * H1 + h], s);
                d = fmaf(xv[f], wd_s[f * H1 + h], d);
            }
            as1[n * H1 + h] = s;
            ad1[n * H1 + h] = d;
        }
    } else if (b < 1152) {
        int n = (b - 896) * 256 + t;
        int bn = batch[n];
        int bp = (n == 0) ? -1 : batch[n - 1];
        for (int g = bp + 1; g <= bn; ++g) gptr[g] = n;
        if (n == NN - 1) {
            for (int g = bn + 1; g <= NG; ++g) gptr[g] = NN;
        }
    } else if (b < 1312) {
        // W1^T -> bf16 A-fragment layout for the expansion MFMA (K=9 pad 32)
        int idx = (b - 1152) * 256 + t;            // 40960 total
        int r  = idx & 7;
        int l  = (idx >> 3) & 63;
        int mt = (idx >> 9) & 7;
        int h  = idx >> 12;
        int f  = ((l >> 4) << 3) + r;
        int c  = mt * 16 + (l & 15);
        W1pT[idx] = (f < FIN) ? f2bf(W1[(size_t)f * KK + h * DD + c]) : (unsigned short)0;
    } else {
        // degree count (deg zeroed by async memset before this kernel)
        int e = (b - 1312) * 256 + t;
        if (e < ET) {
            int d = (e < NE) ? ei[NE + e] : e - NE;
            atomicAdd(&deg[d], 1);
        }
    }
}

// ---- CSR build: coalesced 3-phase scan / scatter -----------------------------
__global__ __launch_bounds__(256) void scan1_kernel(const int* __restrict__ deg,
                                                    int* __restrict__ bsum) {
    __shared__ int sc[256];
    int t = threadIdx.x, b = blockIdx.x;
    sc[t] = deg[b * 256 + t];
    __syncthreads();
    for (int off = 128; off > 0; off >>= 1) {
        if (t < off) sc[t] += sc[t + off];
        __syncthreads();
    }
    if (t == 0) bsum[b] = sc[0];
}

__global__ __launch_bounds__(256) void scan2_kernel(int* __restrict__ bsum,
                                                    int* __restrict__ rowptr) {
    __shared__ int sc[256];
    int t = threadIdx.x;
    int v = bsum[t];
    sc[t] = v;
    __syncthreads();
    for (int off = 1; off < 256; off <<= 1) {
        int u = (t >= off) ? sc[t - off] : 0;
        __syncthreads();
        sc[t] += u;
        __syncthreads();
    }
    bsum[t] = sc[t] - v;               // exclusive prefix
    if (t == 255) rowptr[NN] = sc[255];
}

__global__ __launch_bounds__(256) void scan3_kernel(const int* __restrict__ deg,
                                                    const int* __restrict__ bsum,
                                                    int* __restrict__ rowptr,
                                                    int* __restrict__ cursor) {
    __shared__ int sc[256];
    int t = threadIdx.x, b = blockIdx.x;
    int i = b * 256 + t;
    int v = deg[i];
    sc[t] = v;
    __syncthreads();
    for (int off = 1; off < 256; off <<= 1) {
        int u = (t >= off) ? sc[t - off] : 0;
        __syncthreads();
        sc[t] += u;
        __syncthreads();
    }
    int r = bsum[b] + sc[t] - v;
    rowptr[i] = r;
    cursor[i] = r;
}

__global__ void scatter_kernel(const int* __restrict__ ei, int* __restrict__ cursor,
                               int* __restrict__ elist) {
    int e = blockIdx.x * 256 + threadIdx.x;
    if (e >= ET) return;
    int s, d;
    if (e < NE) { s = ei[e]; d = ei[NE + e]; } else { s = d = e - NE; }
    int pos = atomicAdd(&cursor[d], 1);
    elist[pos] = s;
}

// ---- layer-1 aggregation: per-(node,head), online softmax (round-14 form) ---
// xaggb[(n*H1+h)*32 + f] bf16: f 0..8 = xagg/den, f 9..31 = 0 (K=32 MFMA pad).
__global__ void agg1_kernel(const int* __restrict__ rowptr, const int* __restrict__ elist,
                            const float* __restrict__ x,
                            const float* __restrict__ as1, const float* __restrict__ ad1,
                            unsigned short* __restrict__ xaggb) {
    int idx = blockIdx.x * 256 + threadIdx.x;     // NN*H1
    if (idx >= NN * H1) return;
    int d = idx / H1, h = idx - d * H1;
    int beg = rowptr[d], end = rowptr[d + 1];
    float adh = ad1[d * H1 + h];
    float m = -INFINITY, den = 0.f;
    float xa[FIN] = {};
    for (int j = beg; j < end; ++j) {
        int s = elist[j];
        float v = lrelu(as1[s * H1 + h] + adh);
        if (v > m) {
            float sc = __expf(m - v);
            den *= sc;
#pragma unroll
            for (int f = 0; f < FIN; ++f) xa[f] *= sc;
            m = v;
        }
        float ex = __expf(v - m);
        den += ex;
        const float* xs = &x[(size_t)s * FIN];
#pragma unroll
        for (int f = 0; f < FIN; ++f) xa[f] = fmaf(ex, xs[f], xa[f]);
    }
    float inv = 1.f / (den + 1e-16f);
    unsigned int w[16];
#pragma unroll
    for (int i = 0; i < 16; ++i) w[i] = 0u;
#pragma unroll
    for (int f = 0; f < FIN; ++f) {
        unsigned int bv = f2bf(xa[f] * inv);
        w[f >> 1] |= bv << ((f & 1) * 16);
    }
    uint4* dst = (uint4*)&xaggb[(size_t)idx * 32];
    dst[0] = make_uint4(w[0], w[1], w[2], w[3]);
    dst[1] = make_uint4(w[4], w[5], w[6], w[7]);
    dst[2] = make_uint4(w[8], w[9], w[10], w[11]);
    dst[3] = make_uint4(w[12], w[13], w[14], w[15]);
}

// ---- h2 = elu(xagg@W1 + b1) @ W2, BOTH matmuls on MFMA + alpha2 epilogue ----
// v10: single 16 KB Xs half-tile processed twice per head (expand 64 cols ->
// main K=64), cutting LDS 52->35.8 KB => 4 blocks/CU (32 waves, +33%).
// Expansion role split: wave w -> c-tile (w&3) of the half, node-half (w>>2).
__global__ __launch_bounds__(512, 8) void h2_gemm(
        const unsigned short* __restrict__ xaggb,
        const unsigned short* __restrict__ W1pT,
        const float* __restrict__ b1,
        const unsigned short* __restrict__ W2p,
        const float* __restrict__ a_src2, const float* __restrict__ a_dst2,
        unsigned short* __restrict__ h2b, float* __restrict__ as2,
        float* __restrict__ ad2) {
    __shared__ unsigned short Xs[128 * 64];           // 16 KB, v6 swizzle
    __shared__ unsigned short xsb[2][128 * XSB];      // 18 KB
    __shared__ float as_s[128], ad_s[128];
    const int t = threadIdx.x;
    const int n0 = blockIdx.x * 128;
    const int lane = t & 63;
    const int wvu = __builtin_amdgcn_readfirstlane(t >> 6);   // 0..7
    const int rh = wvu & 1, cq = wvu >> 1;                    // main-GEMM roles
    const int ct = wvu & 3, nh2 = wvu >> 2;                   // expansion roles
    const int rlo = lane & 15, khi = lane >> 4;
    const int srow = t >> 2, sseg = t & 3;                    // xsb stage roles

    if (t < 128) { as_s[t] = 0.f; ad_s[t] = 0.f; }

    f32x4 acc[4][2];
#pragma unroll
    for (int mt = 0; mt < 4; ++mt)
#pragma unroll
        for (int ntl = 0; ntl < 2; ++ntl)
#pragma unroll
            for (int q = 0; q < 4; ++q) acc[mt][ntl][q] = 0.f;

    // prologue: stage head 0's xagg slice
    *(uint4*)&xsb[0][srow * XSB + sseg * 8] =
        *(const uint4*)&xaggb[((size_t)(n0 + srow) * H1 + 0) * 32 + sseg * 8];

    for (int h = 0; h < H1; ++h) {
        const int cur = h & 1;
#pragma unroll
        for (int half = 0; half < 2; ++half) {
            __syncthreads();              // prev Xs reads done; xsb[cur] staged

            // expansion: c-tile ct of this half (16 cols), node-half nh2
            short8v a1 = *(const short8v*)
                &W1pT[(((size_t)h * 8 + half * 4 + ct) * 64 + lane) * 8];
            float4 bv4 = *(const float4*)&b1[h * DD + half * 64 + ct * 16 + khi * 4];
            const int gw7 = ct * 2 + (khi >> 1);               // 16B granule in half
            f32x4 acc2[4];
#pragma unroll
            for (int j = 0; j < 4; ++j) {
                int nt = nh2 * 4 + j;
                short8v bfrag = *(const short8v*)&xsb[cur][(nt * 16 + rlo) * XSB + khi * 8];
                f32x4 zz = {0.f, 0.f, 0.f, 0.f};
                acc2[j] = __builtin_amdgcn_mfma_f32_16x16x32_bf16(a1, bfrag, zz, 0, 0, 0);
            }
#pragma unroll
            for (int j = 0; j < 4; ++j) {
                int nt = nh2 * 4 + j;
                float z0 = acc2[j][0] + bv4.x;
                float z1 = acc2[j][1] + bv4.y;
                float z2 = acc2[j][2] + bv4.z;
                float z3 = acc2[j][3] + bv4.w;
                z0 = z0 > 0.f ? z0 : __expf(z0) - 1.f;
                z1 = z1 > 0.f ? z1 : __expf(z1) - 1.f;
                z2 = z2 > 0.f ? z2 : __expf(z2) - 1.f;
                z3 = z3 > 0.f ? z3 : __expf(z3) - 1.f;
                unsigned int lo = (unsigned int)f2bf(z0) | ((unsigned int)f2bf(z1) << 16);
                unsigned int hi = (unsigned int)f2bf(z2) | ((unsigned int)f2bf(z3) << 16);
                int rown = nt * 16 + rlo;                      // node row
                unsigned offu = rown * 64 + (((gw7 ^ (rown & 7)) << 3) | ((khi & 1) << 2));
                *(uint2*)&Xs[offu] = make_uint2(lo, hi);
            }
            __syncthreads();              // Xs visible

            // stage next head's xagg slice during half-0's main phase
            if (half == 0 && h + 1 < H1) {
                *(uint4*)&xsb[cur ^ 1][srow * XSB + sseg * 8] =
                    *(const uint4*)&xaggb[((size_t)(n0 + srow) * H1 + (h + 1)) * 32 + sseg * 8];
            }

            // main GEMM: this half's K=64 (2 sub-K of 32)
#pragma unroll
            for (int ks2 = 0; ks2 < 2; ++ks2) {
                const int ktabs = h * 4 + half * 2 + ks2;
                const int g7 = ks2 * 4 + khi;                  // granule in half
                short8v bfr[2];
#pragma unroll
                for (int ntl = 0; ntl < 2; ++ntl) {
                    const int nt = cq * 2 + ntl;
                    bfr[ntl] = *(const short8v*)&W2p[(((size_t)ktabs * 8 + nt) * 64 + lane) * 8];
                }
#pragma unroll
                for (int mt = 0; mt < 4; ++mt) {
                    const int row2 = rh * 64 + mt * 16 + rlo;
                    unsigned offu = row2 * 64 + ((g7 ^ (row2 & 7)) << 3);
                    short8v af = *(const short8v*)&Xs[offu];
                    acc[mt][0] = __builtin_amdgcn_mfma_f32_16x16x32_bf16(af, bfr[0], acc[mt][0], 0, 0, 0);
                    acc[mt][1] = __builtin_amdgcn_mfma_f32_16x16x32_bf16(af, bfr[1], acc[mt][1], 0, 0, 0);
                }
            }
        }
    }

    // epilogue: stage acc tile as bf16 into dead Xs (+flat xsb), coalesced copy
    __syncthreads();                      // last half's Xs reads done
    unsigned short* xsbf = &xsb[0][0];    // 18 KB flat >= 16 KB needed
#pragma unroll
    for (int mt = 0; mt < 4; ++mt)
#pragma unroll
        for (int ntl = 0; ntl < 2; ++ntl) {
            int col = cq * 32 + ntl * 16 + rlo;
            unsigned short* Xw = (col < 64) ? Xs : xsbf;
            int c64 = col & 63;
#pragma unroll
            for (int q = 0; q < 4; ++q) {
                int row = rh * 64 + mt * 16 + khi * 4 + q;
                Xw[row * 64 + c64] = f2bf(acc[mt][ntl][q]);
            }
        }
    __syncthreads();
#pragma unroll
    for (int i = 0; i < 4; ++i) {
        int j = i * 512 + t;              // uint4 index over the 128x128 tile
        int row = j >> 4;                 // 16 uint4 per 128-col row
        int c8 = (j & 15) * 8;
        const unsigned short* S = (c8 < 64) ? Xs : xsbf;
        uint4 v = *(const uint4*)&S[row * 64 + (c8 & 63)];
        *(uint4*)&h2b[(size_t)(n0 + row) * DD + c8] = v;
    }

    // fused alpha2 from fp32 accumulators
    float sp[16], dp[16];
#pragma unroll
    for (int mt = 0; mt < 4; ++mt)
#pragma unroll
        for (int q = 0; q < 4; ++q) {
            float a = 0.f, b = 0.f;
#pragma unroll
            for (int ntl = 0; ntl < 2; ++ntl) {
                int col = cq * 32 + ntl * 16 + rlo;
                float v = acc[mt][ntl][q];
                a = fmaf(v, a_src2[col], a);
                b = fmaf(v, a_dst2[col], b);
            }
            sp[mt * 4 + q] = a;
            dp[mt * 4 + q] = b;
        }
#pragma unroll
    for (int off = 1; off < 16; off <<= 1) {
#pragma unroll
        for (int i = 0; i < 16; ++i) {
            sp[i] += __shfl_xor(sp[i], off);
            dp[i] += __shfl_xor(dp[i], off);
        }
    }
    if (rlo == 0) {
#pragma unroll
        for (int mt = 0; mt < 4; ++mt)
#pragma unroll
            for (int q = 0; q < 4; ++q) {
                atomicAdd(&as_s[rh * 64 + mt * 16 + khi * 4 + q], sp[mt * 4 + q]);
                atomicAdd(&ad_s[rh * 64 + mt * 16 + khi * 4 + q], dp[mt * 4 + q]);
            }
    }
    __syncthreads();
    if (t < 128) {
        as2[n0 + t] = as_s[t];
        ad2[n0 + t] = ad_s[t];
    }
}

// ---- layer-2 aggregation (online softmax, bf16 h2) -> x2 (bf16) -------------
__global__ void agg2_kernel(const int* __restrict__ rowptr, const int* __restrict__ elist,
                            const unsigned short* __restrict__ h2b,
                            const float* __restrict__ as2, const float* __restrict__ ad2,
                            const float* __restrict__ b2, unsigned short* __restrict__ x2b) {
    int gid = blockIdx.x * 256 + threadIdx.x;
    int n = gid >> 5, lane = gid & 31;
    if (n >= NN) return;
    int beg = rowptr[n], end = rowptr[n + 1];
    float adn = ad2[n];
    float m = -INFINITY, den = 0.f;
    float4 acc = make_float4(0.f, 0.f, 0.f, 0.f);
    for (int j = beg; j < end; ++j) {
        int s = elist[j];
        float v = lrelu(as2[s] + adn);
        if (v > m) {
            float sc = __expf(m - v);
            den *= sc;
            acc.x *= sc; acc.y *= sc; acc.z *= sc; acc.w *= sc;
            m = v;
        }
        float ex = __expf(v - m);
        den += ex;
        ushort4 hv = *(const ushort4*)&h2b[(size_t)s * DD + lane * 4];
        acc.x = fmaf(ex, bf2f(hv.x), acc.x);
        acc.y = fmaf(ex, bf2f(hv.y), acc.y);
        acc.z = fmaf(ex, bf2f(hv.z), acc.z);
        acc.w = fmaf(ex, bf2f(hv.w), acc.w);
    }
    float inv = 1.f / (den + 1e-16f);
    float4 bv = *(const float4*)&b2[lane * 4];
    ushort4 o;
    o.x = f2bf(eluf(acc.x * inv + bv.x));
    o.y = f2bf(eluf(acc.y * inv + bv.y));
    o.z = f2bf(eluf(acc.z * inv + bv.z));
    o.w = f2bf(eluf(acc.w * inv + bv.w));
    *(ushort4*)&x2b[(size_t)n * DD + lane * 4] = o;
}

// ---- fused pooling + FC: block g pools its node range, then out row g -------
__global__ __launch_bounds__(128) void pool_final_kernel(const int* __restrict__ gptr,
                                                         const unsigned short* __restrict__ x2b,
                                                         const float* __restrict__ Wfc,
                                                         const float* __restrict__ bfc,
                                                         float* __restrict__ out) {
    __shared__ float pl[DD];
    int g = blockIdx.x;
    int c = threadIdx.x;          // 128 channels
    int beg = gptr[g], end = gptr[g + 1];
    float v = -INFINITY;
    for (int n = beg; n < end; ++n)
        v = fmaxf(v, bf2f(x2b[(size_t)n * DD + c]));
    if (beg == end) v = 0.f;      // empty graph -> 0 (isfinite guard)
    pl[c] = v;
    __syncthreads();
    float acc = bfc[c];
#pragma unroll 8
    for (int k = 0; k < DD; ++k)
        acc = fmaf(pl[k], Wfc[k * DD + c], acc);
    out[(size_t)g * DD + c] = acc > 0.f ? acc : 0.f;
}

extern "C" void kernel_launch(void* const* d_in, const int* in_sizes, int n_in,
                              void* d_out, int out_size, void* d_ws, size_t ws_size,
                              hipStream_t stream) {
    const float* x      = (const float*)d_in[0];
    const int*   ei     = (const int*)d_in[1];
    const int*   batch  = (const int*)d_in[3];
    const float* W1     = (const float*)d_in[4];
    const float* a_src1 = (const float*)d_in[5];
    const float* a_dst1 = (const float*)d_in[6];
    const float* b1     = (const float*)d_in[7];
    const float* W2     = (const float*)d_in[8];
    const float* a_src2 = (const float*)d_in[9];
    const float* a_dst2 = (const float*)d_in[10];
    const float* b2     = (const float*)d_in[11];
    const float* Wfc    = (const float*)d_in[12];
    const float* bfc    = (const float*)d_in[13];
    float* out = (float*)d_out;

    // workspace layout — ~90 MB total
    float* wsf    = (float*)d_ws;
    float* as1    = wsf;                                   // NN*H1
    float* ad1    = as1 + (size_t)NN * H1;                 // NN*H1
    float* as2    = ad1 + (size_t)NN * H1;                 // NN
    float* ad2    = as2 + NN;                              // NN
    int*   deg    = (int*)(ad2 + NN);                      // NN
    int*   rowptr = deg + NN;                              // NN+1
    int*   cursor = rowptr + NN + 1;                       // NN
    int*   elist  = cursor + NN;                           // ET
    int*   gptr   = elist + ET;                            // NG+1
    int*   bsum   = gptr + NG + 1;                         // 256
    size_t off = (size_t)((char*)(bsum + 256) - (char*)d_ws);
    off = (off + 15) & ~(size_t)15;
    unsigned short* W2p   = (unsigned short*)((char*)d_ws + off);    // KK*DD bf16
    unsigned short* W1pT  = W2p + (size_t)KK * DD;                   // 40960 bf16
    unsigned short* xaggb = W1pT + 40960;                            // NN*H1*32 bf16
    unsigned short* h2b   = xaggb + (size_t)NN * H1 * 32;            // NN*DD bf16
    unsigned short* x2b   = h2b + (size_t)NN * DD;                   // NN*DD bf16

    hipMemsetAsync(deg, 0, (size_t)NN * sizeof(int), stream);
    setup_kernel     <<<1312 + (ET + 255) / 256, 256, 0, stream>>>(
                        W1, W2, a_src1, a_dst1, x, batch, ei,
                        W2p, W1pT, as1, ad1, deg, gptr);
    scan1_kernel     <<<256, 256, 0, stream>>>(deg, bsum);
    scan2_kernel     <<<1, 256, 0, stream>>>(bsum, rowptr);
    scan3_kernel     <<<256, 256, 0, stream>>>(deg, bsum, rowptr, cursor);
    scatter_kernel   <<<(ET + 255) / 256, 256, 0, stream>>>(ei, cursor, elist);
    agg1_kernel      <<<(NN * H1 + 255) / 256, 256, 0, stream>>>(rowptr, elist, x, as1, ad1, xaggb);
    h2_gemm          <<<NN / 128, 512, 0, stream>>>(xaggb, W1pT, b1, W2p, a_src2, a_dst2,
                                                    h2b, as2, ad2);
    agg2_kernel      <<<(NN * 32) / 256, 256, 0, stream>>>(rowptr, elist, h2b, as2, ad2, b2, x2b);
    pool_final_kernel<<<NG, 128, 0, stream>>>(gptr, x2b, Wfc, bfc, out);
}

// Round 17
// 169.856 us; speedup vs baseline: 1.4707x; 1.4707x over previous
//
#include <hip/hip_runtime.h>
#include <hip/hip_bf16.h>
#include <math.h>

#define NN 65536          // nodes
#define NE 196608         // edges (without self loops)
#define ET (NE + NN)      // edges + self loops = 262144
#define NG 2048           // graphs
#define FIN 9
#define DD 128
#define H1 10
#define KK (H1 * DD)      // 1280
#define LRS 0.2f
#define XSB 36            // xsb row stride (ushorts): 72B rows

typedef __attribute__((ext_vector_type(8))) short short8v;
typedef __attribute__((ext_vector_type(4))) float f32x4;

__device__ __forceinline__ float lrelu(float v) { return v >= 0.f ? v : LRS * v; }
__device__ __forceinline__ float eluf(float v)  { return v > 0.f ? v : expm1f(v); }

// float -> bf16 round-to-nearest-even (3 int ops, no libcall)
__device__ __forceinline__ unsigned short f2bf(float f) {
    unsigned int u = __float_as_uint(f);
    u += 0x7FFFu + ((u >> 16) & 1u);
    return (unsigned short)(u >> 16);
}
__device__ __forceinline__ float bf2f(unsigned short s) {
    return __uint_as_float((unsigned int)s << 16);
}

// ---- setup: packW2 | alpha1+prep | gptr | packW1pT | count (deg pre-zeroed
// ---- by hipMemsetAsync). All branches independent. -------------------------
__global__ __launch_bounds__(256) void setup_kernel(
        const float* __restrict__ W1, const float* __restrict__ W2,
        const float* __restrict__ a_src1, const float* __restrict__ a_dst1,
        const float* __restrict__ x, const int* __restrict__ batch,
        const int* __restrict__ ei,
        unsigned short* __restrict__ W2p, unsigned short* __restrict__ W1pT,
        float* __restrict__ as1, float* __restrict__ ad1,
        int* __restrict__ deg, int* __restrict__ gptr) {
    __shared__ float ws_s[FIN * H1], wd_s[FIN * H1];
    const int b = blockIdx.x;
    const int t = threadIdx.x;
    if (b < 640) {
        // W2 (1280x128 fp32) -> bf16 B-fragment layout
        int idx = b * 256 + t;
        int r  = idx & 7;
        int l  = (idx >> 3) & 63;
        int nt = (idx >> 9) & 7;
        int kt = idx >> 12;
        int k = kt * 32 + ((l >> 4) << 3) + r;
        int n = nt * 16 + (l & 15);
        W2p[idx] = f2bf(W2[(size_t)k * DD + n]);
    } else if (b < 896) {
        if (t < FIN * H1) {
            int f = t / H1, h = t - f * H1;
            float s = 0.f, d = 0.f;
            for (int c = 0; c < DD; ++c) {
                float w = W1[f * KK + h * DD + c];
                s = fmaf(w, a_src1[h * DD + c], s);
                d = fmaf(w, a_dst1[h * DD + c], d);
            }
            ws_s[t] = s;
            wd_s[t] = d;
        }
        __syncthreads();
        int n = (b - 640) * 256 + t;
        float xv[FIN];
#pragma unroll
        for (int f = 0; f < FIN; ++f) xv[f] = x[(size_t)n * FIN + f];
#pragma unroll
        for (int h = 0; h < H1; ++h) {
            float s = 0.f, d = 0.f;
#pragma unroll
            for (int f = 0; f < FIN; ++f) {
                s = fmaf(xv[f], ws_s[f * H1 + h], s);
                d = fmaf(xv[f], wd_s[f * H1 + h], d);
            }
            as1[n * H1 + h] = s;
            ad1[n * H1 + h] = d;
        }
    } else if (b < 1152) {
        int n = (b - 896) * 256 + t;
        int bn = batch[n];
        int bp = (n == 0) ? -1 : batch[n - 1];
        for (int g = bp + 1; g <= bn; ++g) gptr[g] = n;
        if (n == NN - 1) {
            for (int g = bn + 1; g <= NG; ++g) gptr[g] = NN;
        }
    } else if (b < 1312) {
        // W1^T -> bf16 A-fragment layout for the expansion MFMA (K=9 pad 32)
        int idx = (b - 1152) * 256 + t;            // 40960 total
        int r  = idx & 7;
        int l  = (idx >> 3) & 63;
        int mt = (idx >> 9) & 7;
        int h  = idx >> 12;
        int f  = ((l >> 4) << 3) + r;
        int c  = mt * 16 + (l & 15);
        W1pT[idx] = (f < FIN) ? f2bf(W1[(size_t)f * KK + h * DD + c]) : (unsigned short)0;
    } else {
        // degree count (deg zeroed by async memset before this kernel)
        int e = (b - 1312) * 256 + t;
        if (e < ET) {
            int d = (e < NE) ? ei[NE + e] : e - NE;
            atomicAdd(&deg[d], 1);
        }
    }
}

// ---- CSR build: coalesced 3-phase scan / scatter -----------------------------
__global__ __launch_bounds__(256) void scan1_kernel(const int* __restrict__ deg,
                                                    int* __restrict__ bsum) {
    __shared__ int sc[256];
    int t = threadIdx.x, b = blockIdx.x;
    sc[t] = deg[b * 256 + t];
    __syncthreads();
    for (int off = 128; off > 0; off >>= 1) {
        if (t < off) sc[t] += sc[t + off];
        __syncthreads();
    }
    if (t == 0) bsum[b] = sc[0];
}

__global__ __launch_bounds__(256) void scan2_kernel(int* __restrict__ bsum,
                                                    int* __restrict__ rowptr) {
    __shared__ int sc[256];
    int t = threadIdx.x;
    int v = bsum[t];
    sc[t] = v;
    __syncthreads();
    for (int off = 1; off < 256; off <<= 1) {
        int u = (t >= off) ? sc[t - off] : 0;
        __syncthreads();
        sc[t] += u;
        __syncthreads();
    }
    bsum[t] = sc[t] - v;               // exclusive prefix
    if (t == 255) rowptr[NN] = sc[255];
}

__global__ __launch_bounds__(256) void scan3_kernel(const int* __restrict__ deg,
                                                    const int* __restrict__ bsum,
                                                    int* __restrict__ rowptr,
                                                    int* __restrict__ cursor) {
    __shared__ int sc[256];
    int t = threadIdx.x, b = blockIdx.x;
    int i = b * 256 + t;
    int v = deg[i];
    sc[t] = v;
    __syncthreads();
    for (int off = 1; off < 256; off <<= 1) {
        int u = (t >= off) ? sc[t - off] : 0;
        __syncthreads();
        sc[t] += u;
        __syncthreads();
    }
    int r = bsum[b] + sc[t] - v;
    rowptr[i] = r;
    cursor[i] = r;
}

__global__ void scatter_kernel(const int* __restrict__ ei, int* __restrict__ cursor,
                               int* __restrict__ elist) {
    int e = blockIdx.x * 256 + threadIdx.x;
    if (e >= ET) return;
    int s, d;
    if (e < NE) { s = ei[e]; d = ei[NE + e]; } else { s = d = e - NE; }
    int pos = atomicAdd(&cursor[d], 1);
    elist[pos] = s;
}

// ---- layer-1 aggregation: per-(node,head), online softmax (round-14 form) ---
// xaggb[(n*H1+h)*32 + f] bf16: f 0..8 = xagg/den, f 9..31 = 0 (K=32 MFMA pad).
__global__ void agg1_kernel(const int* __restrict__ rowptr, const int* __restrict__ elist,
                            const float* __restrict__ x,
                            const float* __restrict__ as1, const float* __restrict__ ad1,
                            unsigned short* __restrict__ xaggb) {
    int idx = blockIdx.x * 256 + threadIdx.x;     // NN*H1
    if (idx >= NN * H1) return;
    int d = idx / H1, h = idx - d * H1;
    int beg = rowptr[d], end = rowptr[d + 1];
    float adh = ad1[d * H1 + h];
    float m = -INFINITY, den = 0.f;
    float xa[FIN] = {};
    for (int j = beg; j < end; ++j) {
        int s = elist[j];
        float v = lrelu(as1[s * H1 + h] + adh);
        if (v > m) {
            float sc = __expf(m - v);
            den *= sc;
#pragma unroll
            for (int f = 0; f < FIN; ++f) xa[f] *= sc;
            m = v;
        }
        float ex = __expf(v - m);
        den += ex;
        const float* xs = &x[(size_t)s * FIN];
#pragma unroll
        for (int f = 0; f < FIN; ++f) xa[f] = fmaf(ex, xs[f], xa[f]);
    }
    float inv = 1.f / (den + 1e-16f);
    unsigned int w[16];
#pragma unroll
    for (int i = 0; i < 16; ++i) w[i] = 0u;
#pragma unroll
    for (int f = 0; f < FIN; ++f) {
        unsigned int bv = f2bf(xa[f] * inv);
        w[f >> 1] |= bv << ((f & 1) * 16);
    }
    uint4* dst = (uint4*)&xaggb[(size_t)idx * 32];
    dst[0] = make_uint4(w[0], w[1], w[2], w[3]);
    dst[1] = make_uint4(w[4], w[5], w[6], w[7]);
    dst[2] = make_uint4(w[8], w[9], w[10], w[11]);
    dst[3] = make_uint4(w[12], w[13], w[14], w[15]);
}

// ---- h2 = elu(xagg@W1 + b1) @ W2, BOTH matmuls on MFMA + alpha2 epilogue ----
// v9 (round-14 measured best): Xs split into two 64-col halves (v6 swizzle);
// xsb double-buffered; bf16 h2 written via LDS re-stage, coalesced uint4.
__global__ __launch_bounds__(512, 4) void h2_gemm(
        const unsigned short* __restrict__ xaggb,
        const unsigned short* __restrict__ W1pT,
        const float* __restrict__ b1,
        const unsigned short* __restrict__ W2p,
        const float* __restrict__ a_src2, const float* __restrict__ a_dst2,
        unsigned short* __restrict__ h2b, float* __restrict__ as2,
        float* __restrict__ ad2) {
    __shared__ unsigned short Xs0[128 * 64];          // 16 KB, v6 swizzle
    __shared__ unsigned short Xs1[128 * 64];          // 16 KB
    __shared__ unsigned short xsb[2][128 * XSB];      // 2 x 9 KB
    __shared__ float as_s[128], ad_s[128];
    const int t = threadIdx.x;
    const int n0 = blockIdx.x * 128;
    const int lane = t & 63;
    const int wvu = __builtin_amdgcn_readfirstlane(t >> 6);   // 0..7
    const int rh = wvu & 1, cq = wvu >> 1;                    // main-GEMM roles
    const int rlo = lane & 15, khi = lane >> 4;
    const int srow = t >> 2, sseg = t & 3;                    // xsb stage roles

    if (t < 128) { as_s[t] = 0.f; ad_s[t] = 0.f; }

    f32x4 acc[4][2];
#pragma unroll
    for (int mt = 0; mt < 4; ++mt)
#pragma unroll
        for (int ntl = 0; ntl < 2; ++ntl)
#pragma unroll
            for (int q = 0; q < 4; ++q) acc[mt][ntl][q] = 0.f;

    // prologue: stage head 0's xagg slice
    *(uint4*)&xsb[0][srow * XSB + sseg * 8] =
        *(const uint4*)&xaggb[((size_t)(n0 + srow) * H1 + 0) * 32 + sseg * 8];

    for (int h = 0; h < H1; ++h) {
        const int cur = h & 1;
        __syncthreads();                  // xsb[cur] staged; prev Xs reads done

        // expansion: wave owns c-tile wvu (16 cols of x1 within this head)
        short8v a1 = *(const short8v*)&W1pT[(((size_t)h * 8 + wvu) * 64 + lane) * 8];
        float4 bv4 = *(const float4*)&b1[h * DD + wvu * 16 + khi * 4];
        unsigned short* XsW = (wvu >> 2) ? Xs1 : Xs0;          // write half
        const int gw7 = (wvu * 2 + (khi >> 1)) & 7;            // granule in half
#pragma unroll
        for (int nh = 0; nh < 2; ++nh) {
            f32x4 acc2[4];
#pragma unroll
            for (int j = 0; j < 4; ++j) {
                int nt = nh * 4 + j;
                short8v bfrag = *(const short8v*)&xsb[cur][(nt * 16 + rlo) * XSB + khi * 8];
                f32x4 zz = {0.f, 0.f, 0.f, 0.f};
                acc2[j] = __builtin_amdgcn_mfma_f32_16x16x32_bf16(a1, bfrag, zz, 0, 0, 0);
            }
#pragma unroll
            for (int j = 0; j < 4; ++j) {
                int nt = nh * 4 + j;
                float z0 = acc2[j][0] + bv4.x;
                float z1 = acc2[j][1] + bv4.y;
                float z2 = acc2[j][2] + bv4.z;
                float z3 = acc2[j][3] + bv4.w;
                z0 = z0 > 0.f ? z0 : __expf(z0) - 1.f;
                z1 = z1 > 0.f ? z1 : __expf(z1) - 1.f;
                z2 = z2 > 0.f ? z2 : __expf(z2) - 1.f;
                z3 = z3 > 0.f ? z3 : __expf(z3) - 1.f;
                unsigned int lo = (unsigned int)f2bf(z0) | ((unsigned int)f2bf(z1) << 16);
                unsigned int hi = (unsigned int)f2bf(z2) | ((unsigned int)f2bf(z3) << 16);
                int rown = nt * 16 + rlo;                      // node row
                unsigned offu = rown * 64 + (((gw7 ^ (rown & 7)) << 3) | ((khi & 1) << 2));
                *(uint2*)&XsW[offu] = make_uint2(lo, hi);
            }
        }
        __syncthreads();                  // Xs visible

        // stage next head's xagg slice into the other xsb buffer (overlaps GEMM)
        if (h + 1 < H1) {
            *(uint4*)&xsb[cur ^ 1][srow * XSB + sseg * 8] =
                *(const uint4*)&xaggb[((size_t)(n0 + srow) * H1 + (h + 1)) * 32 + sseg * 8];
        }

        // main GEMM: this head's K=128 (4 sub-K of 32; ks<2 -> Xs0, ks>=2 -> Xs1)
#pragma unroll
        for (int ks = 0; ks < 4; ++ks) {
            const int ktabs = h * 4 + ks;
            const unsigned short* XsR = (ks >> 1) ? Xs1 : Xs0;
            const int g7 = (ks & 1) * 4 + khi;                 // granule in half
            short8v bfr[2];
#pragma unroll
            for (int ntl = 0; ntl < 2; ++ntl) {
                const int nt = cq * 2 + ntl;
                bfr[ntl] = *(const short8v*)&W2p[(((size_t)ktabs * 8 + nt) * 64 + lane) * 8];
            }
#pragma unroll
            for (int mt = 0; mt < 4; ++mt) {
                const int row2 = rh * 64 + mt * 16 + rlo;
                unsigned offu = row2 * 64 + ((g7 ^ (row2 & 7)) << 3);
                short8v af = *(const short8v*)&XsR[offu];
                acc[mt][0] = __builtin_amdgcn_mfma_f32_16x16x32_bf16(af, bfr[0], acc[mt][0], 0, 0, 0);
                acc[mt][1] = __builtin_amdgcn_mfma_f32_16x16x32_bf16(af, bfr[1], acc[mt][1], 0, 0, 0);
            }
        }
    }

    // epilogue: stage acc tile as bf16 into dead Xs buffers, then coalesced copy
    __syncthreads();                      // last head's Xs reads done
#pragma unroll
    for (int mt = 0; mt < 4; ++mt)
#pragma unroll
        for (int ntl = 0; ntl < 2; ++ntl) {
            int col = cq * 32 + ntl * 16 + rlo;
            unsigned short* Xw = (col < 64) ? Xs0 : Xs1;
            int c64 = col & 63;
#pragma unroll
            for (int q = 0; q < 4; ++q) {
                int row = rh * 64 + mt * 16 + khi * 4 + q;
                Xw[row * 64 + c64] = f2bf(acc[mt][ntl][q]);
            }
        }
    __syncthreads();
#pragma unroll
    for (int i = 0; i < 4; ++i) {
        int j = i * 512 + t;              // uint4 index over the 128x128 tile
        int row = j >> 4;                 // 16 uint4 per 128-col row
        int c8 = (j & 15) * 8;
        const unsigned short* S = (c8 < 64) ? Xs0 : Xs1;
        uint4 v = *(const uint4*)&S[row * 64 + (c8 & 63)];
        *(uint4*)&h2b[(size_t)(n0 + row) * DD + c8] = v;
    }

    // fused alpha2 from fp32 accumulators
    float sp[16], dp[16];
#pragma unroll
    for (int mt = 0; mt < 4; ++mt)
#pragma unroll
        for (int q = 0; q < 4; ++q) {
            float a = 0.f, b = 0.f;
#pragma unroll
            for (int ntl = 0; ntl < 2; ++ntl) {
                int col = cq * 32 + ntl * 16 + rlo;
                float v = acc[mt][ntl][q];
                a = fmaf(v, a_src2[col], a);
                b = fmaf(v, a_dst2[col], b);
            }
            sp[mt * 4 + q] = a;
            dp[mt * 4 + q] = b;
        }
#pragma unroll
    for (int off = 1; off < 16; off <<= 1) {
#pragma unroll
        for (int i = 0; i < 16; ++i) {
            sp[i] += __shfl_xor(sp[i], off);
            dp[i] += __shfl_xor(dp[i], off);
        }
    }
    if (rlo == 0) {
#pragma unroll
        for (int mt = 0; mt < 4; ++mt)
#pragma unroll
            for (int q = 0; q < 4; ++q) {
                atomicAdd(&as_s[rh * 64 + mt * 16 + khi * 4 + q], sp[mt * 4 + q]);
                atomicAdd(&ad_s[rh * 64 + mt * 16 + khi * 4 + q], dp[mt * 4 + q]);
            }
    }
    __syncthreads();
    if (t < 128) {
        as2[n0 + t] = as_s[t];
        ad2[n0 + t] = ad_s[t];
    }
}

// ---- layer-2 aggregation (online softmax, bf16 h2) -> x2 (bf16) -------------
__global__ void agg2_kernel(const int* __restrict__ rowptr, const int* __restrict__ elist,
                            const unsigned short* __restrict__ h2b,
                            const float* __restrict__ as2, const float* __restrict__ ad2,
                            const float* __restrict__ b2, unsigned short* __restrict__ x2b) {
    int gid = blockIdx.x * 256 + threadIdx.x;
    int n = gid >> 5, lane = gid & 31;
    if (n >= NN) return;
    int beg = rowptr[n], end = rowptr[n + 1];
    float adn = ad2[n];
    float m = -INFINITY, den = 0.f;
    float4 acc = make_float4(0.f, 0.f, 0.f, 0.f);
    for (int j = beg; j < end; ++j) {
        int s = elist[j];
        float v = lrelu(as2[s] + adn);
        if (v > m) {
            float sc = __expf(m - v);
            den *= sc;
            acc.x *= sc; acc.y *= sc; acc.z *= sc; acc.w *= sc;
            m = v;
        }
        float ex = __expf(v - m);
        den += ex;
        ushort4 hv = *(const ushort4*)&h2b[(size_t)s * DD + lane * 4];
        acc.x = fmaf(ex, bf2f(hv.x), acc.x);
        acc.y = fmaf(ex, bf2f(hv.y), acc.y);
        acc.z = fmaf(ex, bf2f(hv.z), acc.z);
        acc.w = fmaf(ex, bf2f(hv.w), acc.w);
    }
    float inv = 1.f / (den + 1e-16f);
    float4 bv = *(const float4*)&b2[lane * 4];
    ushort4 o;
    o.x = f2bf(eluf(acc.x * inv + bv.x));
    o.y = f2bf(eluf(acc.y * inv + bv.y));
    o.z = f2bf(eluf(acc.z * inv + bv.z));
    o.w = f2bf(eluf(acc.w * inv + bv.w));
    *(ushort4*)&x2b[(size_t)n * DD + lane * 4] = o;
}

// ---- fused pooling + FC: block g pools its node range, then out row g -------
__global__ __launch_bounds__(128) void pool_final_kernel(const int* __restrict__ gptr,
                                                         const unsigned short* __restrict__ x2b,
                                                         const float* __restrict__ Wfc,
                                                         const float* __restrict__ bfc,
                                                         float* __restrict__ out) {
    __shared__ float pl[DD];
    int g = blockIdx.x;
    int c = threadIdx.x;          // 128 channels
    int beg = gptr[g], end = gptr[g + 1];
    float v = -INFINITY;
    for (int n = beg; n < end; ++n)
        v = fmaxf(v, bf2f(x2b[(size_t)n * DD + c]));
    if (beg == end) v = 0.f;      // empty graph -> 0 (isfinite guard)
    pl[c] = v;
    __syncthreads();
    float acc = bfc[c];
#pragma unroll 8
    for (int k = 0; k < DD; ++k)
        acc = fmaf(pl[k], Wfc[k * DD + c], acc);
    out[(size_t)g * DD + c] = acc > 0.f ? acc : 0.f;
}

extern "C" void kernel_launch(void* const* d_in, const int* in_sizes, int n_in,
                              void* d_out, int out_size, void* d_ws, size_t ws_size,
                              hipStream_t stream) {
    const float* x      = (const float*)d_in[0];
    const int*   ei     = (const int*)d_in[1];
    const int*   batch  = (const int*)d_in[3];
    const float* W1     = (const float*)d_in[4];
    const float* a_src1 = (const float*)d_in[5];
    const float* a_dst1 = (const float*)d_in[6];
    const float* b1     = (const float*)d_in[7];
    const float* W2     = (const float*)d_in[8];
    const float* a_src2 = (const float*)d_in[9];
    const float* a_dst2 = (const float*)d_in[10];
    const float* b2     = (const float*)d_in[11];
    const float* Wfc    = (const float*)d_in[12];
    const float* bfc    = (const float*)d_in[13];
    float* out = (float*)d_out;

    // workspace layout — ~90 MB total
    float* wsf    = (float*)d_ws;
    float* as1    = wsf;                                   // NN*H1
    float* ad1    = as1 + (size_t)NN * H1;                 // NN*H1
    float* as2    = ad1 + (size_t)NN * H1;                 // NN
    float* ad2    = as2 + NN;                              // NN
    int*   deg    = (int*)(ad2 + NN);                      // NN
    int*   rowptr = deg + NN;                              // NN+1
    int*   cursor = rowptr + NN + 1;                       // NN
    int*   elist  = cursor + NN;                           // ET
    int*   gptr   = elist + ET;                            // NG+1
    int*   bsum   = gptr + NG + 1;                         // 256
    size_t off = (size_t)((char*)(bsum + 256) - (char*)d_ws);
    off = (off + 15) & ~(size_t)15;
    unsigned short* W2p   = (unsigned short*)((char*)d_ws + off);    // KK*DD bf16
    unsigned short* W1pT  = W2p + (size_t)KK * DD;                   // 40960 bf16
    unsigned short* xaggb = W1pT + 40960;                            // NN*H1*32 bf16
    unsigned short* h2b   = xaggb + (size_t)NN * H1 * 32;            // NN*DD bf16
    unsigned short* x2b   = h2b + (size_t)NN * DD;                   // NN*DD bf16

    hipMemsetAsync(deg, 0, (size_t)NN * sizeof(int), stream);
    setup_kernel     <<<1312 + (ET + 255) / 256, 256, 0, stream>>>(
                        W1, W2, a_src1, a_dst1, x, batch, ei,
                        W2p, W1pT, as1, ad1, deg, gptr);
    scan1_kernel     <<<256, 256, 0, stream>>>(deg, bsum);
    scan2_kernel     <<<1, 256, 0, stream>>>(bsum, rowptr);
    scan3_kernel     <<<256, 256, 0, stream>>>(deg, bsum, rowptr, cursor);
    scatter_kernel   <<<(ET + 255) / 256, 256, 0, stream>>>(ei, cursor, elist);
    agg1_kernel      <<<(NN * H1 + 255) / 256, 256, 0, stream>>>(rowptr, elist, x, as1, ad1, xaggb);
    h2_gemm          <<<NN / 128, 512, 0, stream>>>(xaggb, W1pT, b1, W2p, a_src2, a_dst2,
                                                    h2b, as2, ad2);
    agg2_kernel      <<<(NN * 32) / 256, 256, 0, stream>>>(rowptr, elist, h2b, as2, ad2, b2, x2b);
    pool_final_kernel<<<NG, 128, 0, stream>>>(gptr, x2b, Wfc, bfc, out);
}

// Round 18
// 163.807 us; speedup vs baseline: 1.5251x; 1.0369x over previous
//
#include <hip/hip_runtime.h>
#include <hip/hip_bf16.h>
#include <math.h>

#define NN 65536          // nodes
#define NE 196608         // edges (without self loops)
#define ET (NE + NN)      // edges + self loops = 262144
#define NG 2048           // graphs
#define FIN 9
#define DD 128
#define H1 10
#define KK (H1 * DD)      // 1280
#define LRS 0.2f
#define XSB 36            // xsb row stride (ushorts): 72B rows

typedef __attribute__((ext_vector_type(8))) short short8v;
typedef __attribute__((ext_vector_type(4))) float f32x4;

__device__ __forceinline__ float lrelu(float v) { return v >= 0.f ? v : LRS * v; }
__device__ __forceinline__ float eluf(float v)  { return v > 0.f ? v : expm1f(v); }

// float -> bf16 round-to-nearest-even (3 int ops, no libcall)
__device__ __forceinline__ unsigned short f2bf(float f) {
    unsigned int u = __float_as_uint(f);
    u += 0x7FFFu + ((u >> 16) & 1u);
    return (unsigned short)(u >> 16);
}
__device__ __forceinline__ float bf2f(unsigned short s) {
    return __uint_as_float((unsigned int)s << 16);
}

// ---- setup: packW2 | alpha1+prep | gptr | packW1pT | count (deg pre-zeroed
// ---- by hipMemsetAsync). All branches independent. -------------------------
__global__ __launch_bounds__(256) void setup_kernel(
        const float* __restrict__ W1, const float* __restrict__ W2,
        const float* __restrict__ a_src1, const float* __restrict__ a_dst1,
        const float* __restrict__ x, const int* __restrict__ batch,
        const int* __restrict__ ei,
        unsigned short* __restrict__ W2p, unsigned short* __restrict__ W1pT,
        float* __restrict__ as1, float* __restrict__ ad1,
        int* __restrict__ deg, int* __restrict__ gptr) {
    __shared__ float ws_s[FIN * H1], wd_s[FIN * H1];
    const int b = blockIdx.x;
    const int t = threadIdx.x;
    if (b < 640) {
        // W2 (1280x128 fp32) -> bf16 B-fragment layout
        int idx = b * 256 + t;
        int r  = idx & 7;
        int l  = (idx >> 3) & 63;
        int nt = (idx >> 9) & 7;
        int kt = idx >> 12;
        int k = kt * 32 + ((l >> 4) << 3) + r;
        int n = nt * 16 + (l & 15);
        W2p[idx] = f2bf(W2[(size_t)k * DD + n]);
    } else if (b < 896) {
        if (t < FIN * H1) {
            int f = t / H1, h = t - f * H1;
            float s = 0.f, d = 0.f;
            for (int c = 0; c < DD; ++c) {
                float w = W1[f * KK + h * DD + c];
                s = fmaf(w, a_src1[h * DD + c], s);
                d = fmaf(w, a_dst1[h * DD + c], d);
            }
            ws_s[t] = s;
            wd_s[t] = d;
        }
        __syncthreads();
        int n = (b - 640) * 256 + t;
        float xv[FIN];
#pragma unroll
        for (int f = 0; f < FIN; ++f) xv[f] = x[(size_t)n * FIN + f];
#pragma unroll
        for (int h = 0; h < H1; ++h) {
            float s = 0.f, d = 0.f;
#pragma unroll
            for (int f = 0; f < FIN; ++f) {
                s = fmaf(xv[f], ws_s[f * H1 + h], s);
                d = fmaf(xv[f], wd_s[f * H1 + h], d);
            }
            as1[n * H1 + h] = s;
            ad1[n * H1 + h] = d;
        }
    } else if (b < 1152) {
        int n = (b - 896) * 256 + t;
        int bn = batch[n];
        int bp = (n == 0) ? -1 : batch[n - 1];
        for (int g = bp + 1; g <= bn; ++g) gptr[g] = n;
        if (n == NN - 1) {
            for (int g = bn + 1; g <= NG; ++g) gptr[g] = NN;
        }
    } else if (b < 1312) {
        // W1^T -> bf16 A-fragment layout for the expansion MFMA (K=9 pad 32)
        int idx = (b - 1152) * 256 + t;            // 40960 total
        int r  = idx & 7;
        int l  = (idx >> 3) & 63;
        int mt = (idx >> 9) & 7;
        int h  = idx >> 12;
        int f  = ((l >> 4) << 3) + r;
        int c  = mt * 16 + (l & 15);
        W1pT[idx] = (f < FIN) ? f2bf(W1[(size_t)f * KK + h * DD + c]) : (unsigned short)0;
    } else {
        // degree count (deg zeroed by async memset before this kernel)
        int e = (b - 1312) * 256 + t;
        if (e < ET) {
            int d = (e < NE) ? ei[NE + e] : e - NE;
            atomicAdd(&deg[d], 1);
        }
    }
}

// ---- CSR build: coalesced 3-phase scan / scatter -----------------------------
__global__ __launch_bounds__(256) void scan1_kernel(const int* __restrict__ deg,
                                                    int* __restrict__ bsum) {
    __shared__ int sc[256];
    int t = threadIdx.x, b = blockIdx.x;
    sc[t] = deg[b * 256 + t];
    __syncthreads();
    for (int off = 128; off > 0; off >>= 1) {
        if (t < off) sc[t] += sc[t + off];
        __syncthreads();
    }
    if (t == 0) bsum[b] = sc[0];
}

__global__ __launch_bounds__(256) void scan2_kernel(int* __restrict__ bsum,
                                                    int* __restrict__ rowptr) {
    __shared__ int sc[256];
    int t = threadIdx.x;
    int v = bsum[t];
    sc[t] = v;
    __syncthreads();
    for (int off = 1; off < 256; off <<= 1) {
        int u = (t >= off) ? sc[t - off] : 0;
        __syncthreads();
        sc[t] += u;
        __syncthreads();
    }
    bsum[t] = sc[t] - v;               // exclusive prefix
    if (t == 255) rowptr[NN] = sc[255];
}

__global__ __launch_bounds__(256) void scan3_kernel(const int* __restrict__ deg,
                                                    const int* __restrict__ bsum,
                                                    int* __restrict__ rowptr,
                                                    int* __restrict__ cursor) {
    __shared__ int sc[256];
    int t = threadIdx.x, b = blockIdx.x;
    int i = b * 256 + t;
    int v = deg[i];
    sc[t] = v;
    __syncthreads();
    for (int off = 1; off < 256; off <<= 1) {
        int u = (t >= off) ? sc[t - off] : 0;
        __syncthreads();
        sc[t] += u;
        __syncthreads();
    }
    int r = bsum[b] + sc[t] - v;
    rowptr[i] = r;
    cursor[i] = r;
}

__global__ void scatter_kernel(const int* __restrict__ ei, int* __restrict__ cursor,
                               int* __restrict__ elist) {
    int e = blockIdx.x * 256 + threadIdx.x;
    if (e >= ET) return;
    int s, d;
    if (e < NE) { s = ei[e]; d = ei[NE + e]; } else { s = d = e - NE; }
    int pos = atomicAdd(&cursor[d], 1);
    elist[pos] = s;
}

// ---- layer-1 aggregation: per-(node,head), online softmax, PIPELINED --------
// 1-ahead prefetch: iteration j issues elist/as1/x loads for j+1 while
// computing with j's registers. Every node has >=1 edge (self-loop).
__global__ void agg1_kernel(const int* __restrict__ rowptr, const int* __restrict__ elist,
                            const float* __restrict__ x,
                            const float* __restrict__ as1, const float* __restrict__ ad1,
                            unsigned short* __restrict__ xaggb) {
    int idx = blockIdx.x * 256 + threadIdx.x;     // NN*H1
    if (idx >= NN * H1) return;
    int d = idx / H1, h = idx - d * H1;
    int beg = rowptr[d], end = rowptr[d + 1];
    float adh = ad1[d * H1 + h];
    float m = -INFINITY, den = 0.f;
    float xa[FIN] = {};
    // prologue: load edge `beg`
    {
        int s0 = elist[beg];
        float asv = as1[s0 * H1 + h];
        float xs[FIN];
#pragma unroll
        for (int f = 0; f < FIN; ++f) xs[f] = x[(size_t)s0 * FIN + f];
        for (int j = beg; j < end; ++j) {
            // prefetch next edge's data while computing current
            float asn = 0.f, xn[FIN];
            if (j + 1 < end) {
                int sn = elist[j + 1];
                asn = as1[sn * H1 + h];
#pragma unroll
                for (int f = 0; f < FIN; ++f) xn[f] = x[(size_t)sn * FIN + f];
            }
            float v = lrelu(asv + adh);
            if (v > m) {
                float sc = __expf(m - v);
                den *= sc;
#pragma unroll
                for (int f = 0; f < FIN; ++f) xa[f] *= sc;
                m = v;
            }
            float ex = __expf(v - m);
            den += ex;
#pragma unroll
            for (int f = 0; f < FIN; ++f) xa[f] = fmaf(ex, xs[f], xa[f]);
            if (j + 1 < end) {
                asv = asn;
#pragma unroll
                for (int f = 0; f < FIN; ++f) xs[f] = xn[f];
            }
        }
    }
    float inv = 1.f / (den + 1e-16f);
    unsigned int w[16];
#pragma unroll
    for (int i = 0; i < 16; ++i) w[i] = 0u;
#pragma unroll
    for (int f = 0; f < FIN; ++f) {
        unsigned int bv = f2bf(xa[f] * inv);
        w[f >> 1] |= bv << ((f & 1) * 16);
    }
    uint4* dst = (uint4*)&xaggb[(size_t)idx * 32];
    dst[0] = make_uint4(w[0], w[1], w[2], w[3]);
    dst[1] = make_uint4(w[4], w[5], w[6], w[7]);
    dst[2] = make_uint4(w[8], w[9], w[10], w[11]);
    dst[3] = make_uint4(w[12], w[13], w[14], w[15]);
}

// ---- h2 = elu(xagg@W1 + b1) @ W2, BOTH matmuls on MFMA + alpha2 epilogue ----
// v9 (round-14 measured best): Xs split into two 64-col halves (v6 swizzle);
// xsb double-buffered; bf16 h2 written via LDS re-stage, coalesced uint4.
__global__ __launch_bounds__(512, 4) void h2_gemm(
        const unsigned short* __restrict__ xaggb,
        const unsigned short* __restrict__ W1pT,
        const float* __restrict__ b1,
        const unsigned short* __restrict__ W2p,
        const float* __restrict__ a_src2, const float* __restrict__ a_dst2,
        unsigned short* __restrict__ h2b, float* __restrict__ as2,
        float* __restrict__ ad2) {
    __shared__ unsigned short Xs0[128 * 64];          // 16 KB, v6 swizzle
    __shared__ unsigned short Xs1[128 * 64];          // 16 KB
    __shared__ unsigned short xsb[2][128 * XSB];      // 2 x 9 KB
    __shared__ float as_s[128], ad_s[128];
    const int t = threadIdx.x;
    const int n0 = blockIdx.x * 128;
    const int lane = t & 63;
    const int wvu = __builtin_amdgcn_readfirstlane(t >> 6);   // 0..7
    const int rh = wvu & 1, cq = wvu >> 1;                    // main-GEMM roles
    const int rlo = lane & 15, khi = lane >> 4;
    const int srow = t >> 2, sseg = t & 3;                    // xsb stage roles

    if (t < 128) { as_s[t] = 0.f; ad_s[t] = 0.f; }

    f32x4 acc[4][2];
#pragma unroll
    for (int mt = 0; mt < 4; ++mt)
#pragma unroll
        for (int ntl = 0; ntl < 2; ++ntl)
#pragma unroll
            for (int q = 0; q < 4; ++q) acc[mt][ntl][q] = 0.f;

    // prologue: stage head 0's xagg slice
    *(uint4*)&xsb[0][srow * XSB + sseg * 8] =
        *(const uint4*)&xaggb[((size_t)(n0 + srow) * H1 + 0) * 32 + sseg * 8];

    for (int h = 0; h < H1; ++h) {
        const int cur = h & 1;
        __syncthreads();                  // xsb[cur] staged; prev Xs reads done

        // expansion: wave owns c-tile wvu (16 cols of x1 within this head)
        short8v a1 = *(const short8v*)&W1pT[(((size_t)h * 8 + wvu) * 64 + lane) * 8];
        float4 bv4 = *(const float4*)&b1[h * DD + wvu * 16 + khi * 4];
        unsigned short* XsW = (wvu >> 2) ? Xs1 : Xs0;          // write half
        const int gw7 = (wvu * 2 + (khi >> 1)) & 7;            // granule in half
#pragma unroll
        for (int nh = 0; nh < 2; ++nh) {
            f32x4 acc2[4];
#pragma unroll
            for (int j = 0; j < 4; ++j) {
                int nt = nh * 4 + j;
                short8v bfrag = *(const short8v*)&xsb[cur][(nt * 16 + rlo) * XSB + khi * 8];
                f32x4 zz = {0.f, 0.f, 0.f, 0.f};
                acc2[j] = __builtin_amdgcn_mfma_f32_16x16x32_bf16(a1, bfrag, zz, 0, 0, 0);
            }
#pragma unroll
            for (int j = 0; j < 4; ++j) {
                int nt = nh * 4 + j;
                float z0 = acc2[j][0] + bv4.x;
                float z1 = acc2[j][1] + bv4.y;
                float z2 = acc2[j][2] + bv4.z;
                float z3 = acc2[j][3] + bv4.w;
                z0 = z0 > 0.f ? z0 : __expf(z0) - 1.f;
                z1 = z1 > 0.f ? z1 : __expf(z1) - 1.f;
                z2 = z2 > 0.f ? z2 : __expf(z2) - 1.f;
                z3 = z3 > 0.f ? z3 : __expf(z3) - 1.f;
                unsigned int lo = (unsigned int)f2bf(z0) | ((unsigned int)f2bf(z1) << 16);
                unsigned int hi = (unsigned int)f2bf(z2) | ((unsigned int)f2bf(z3) << 16);
                int rown = nt * 16 + rlo;                      // node row
                unsigned offu = rown * 64 + (((gw7 ^ (rown & 7)) << 3) | ((khi & 1) << 2));
                *(uint2*)&XsW[offu] = make_uint2(lo, hi);
            }
        }
        __syncthreads();                  // Xs visible

        // stage next head's xagg slice into the other xsb buffer (overlaps GEMM)
        if (h + 1 < H1) {
            *(uint4*)&xsb[cur ^ 1][srow * XSB + sseg * 8] =
                *(const uint4*)&xaggb[((size_t)(n0 + srow) * H1 + (h + 1)) * 32 + sseg * 8];
        }

        // main GEMM: this head's K=128 (4 sub-K of 32; ks<2 -> Xs0, ks>=2 -> Xs1)
#pragma unroll
        for (int ks = 0; ks < 4; ++ks) {
            const int ktabs = h * 4 + ks;
            const unsigned short* XsR = (ks >> 1) ? Xs1 : Xs0;
            const int g7 = (ks & 1) * 4 + khi;                 // granule in half
            short8v bfr[2];
#pragma unroll
            for (int ntl = 0; ntl < 2; ++ntl) {
                const int nt = cq * 2 + ntl;
                bfr[ntl] = *(const short8v*)&W2p[(((size_t)ktabs * 8 + nt) * 64 + lane) * 8];
            }
#pragma unroll
            for (int mt = 0; mt < 4; ++mt) {
                const int row2 = rh * 64 + mt * 16 + rlo;
                unsigned offu = row2 * 64 + ((g7 ^ (row2 & 7)) << 3);
                short8v af = *(const short8v*)&XsR[offu];
                acc[mt][0] = __builtin_amdgcn_mfma_f32_16x16x32_bf16(af, bfr[0], acc[mt][0], 0, 0, 0);
                acc[mt][1] = __builtin_amdgcn_mfma_f32_16x16x32_bf16(af, bfr[1], acc[mt][1], 0, 0, 0);
            }
        }
    }

    // epilogue: stage acc tile as bf16 into dead Xs buffers, then coalesced copy
    __syncthreads();                      // last head's Xs reads done
#pragma unroll
    for (int mt = 0; mt < 4; ++mt)
#pragma unroll
        for (int ntl = 0; ntl < 2; ++ntl) {
            int col = cq * 32 + ntl * 16 + rlo;
            unsigned short* Xw = (col < 64) ? Xs0 : Xs1;
            int c64 = col & 63;
#pragma unroll
            for (int q = 0; q < 4; ++q) {
                int row = rh * 64 + mt * 16 + khi * 4 + q;
                Xw[row * 64 + c64] = f2bf(acc[mt][ntl][q]);
            }
        }
    __syncthreads();
#pragma unroll
    for (int i = 0; i < 4; ++i) {
        int j = i * 512 + t;              // uint4 index over the 128x128 tile
        int row = j >> 4;                 // 16 uint4 per 128-col row
        int c8 = (j & 15) * 8;
        const unsigned short* S = (c8 < 64) ? Xs0 : Xs1;
        uint4 v = *(const uint4*)&S[row * 64 + (c8 & 63)];
        *(uint4*)&h2b[(size_t)(n0 + row) * DD + c8] = v;
    }

    // fused alpha2 from fp32 accumulators
    float sp[16], dp[16];
#pragma unroll
    for (int mt = 0; mt < 4; ++mt)
#pragma unroll
        for (int q = 0; q < 4; ++q) {
            float a = 0.f, b = 0.f;
#pragma unroll
            for (int ntl = 0; ntl < 2; ++ntl) {
                int col = cq * 32 + ntl * 16 + rlo;
                float v = acc[mt][ntl][q];
                a = fmaf(v, a_src2[col], a);
                b = fmaf(v, a_dst2[col], b);
            }
            sp[mt * 4 + q] = a;
            dp[mt * 4 + q] = b;
        }
#pragma unroll
    for (int off = 1; off < 16; off <<= 1) {
#pragma unroll
        for (int i = 0; i < 16; ++i) {
            sp[i] += __shfl_xor(sp[i], off);
            dp[i] += __shfl_xor(dp[i], off);
        }
    }
    if (rlo == 0) {
#pragma unroll
        for (int mt = 0; mt < 4; ++mt)
#pragma unroll
            for (int q = 0; q < 4; ++q) {
                atomicAdd(&as_s[rh * 64 + mt * 16 + khi * 4 + q], sp[mt * 4 + q]);
                atomicAdd(&ad_s[rh * 64 + mt * 16 + khi * 4 + q], dp[mt * 4 + q]);
            }
    }
    __syncthreads();
    if (t < 128) {
        as2[n0 + t] = as_s[t];
        ad2[n0 + t] = ad_s[t];
    }
}

// ---- layer-2 aggregation (online softmax, bf16 h2) -> x2 (bf16), PIPELINED --
__global__ void agg2_kernel(const int* __restrict__ rowptr, const int* __restrict__ elist,
                            const unsigned short* __restrict__ h2b,
                            const float* __restrict__ as2, const float* __restrict__ ad2,
                            const float* __restrict__ b2, unsigned short* __restrict__ x2b) {
    int gid = blockIdx.x * 256 + threadIdx.x;
    int n = gid >> 5, lane = gid & 31;
    if (n >= NN) return;
    int beg = rowptr[n], end = rowptr[n + 1];
    float adn = ad2[n];
    float m = -INFINITY, den = 0.f;
    float4 acc = make_float4(0.f, 0.f, 0.f, 0.f);
    // prologue: load edge `beg` (every node has >=1 edge via self-loop)
    {
        int s0 = elist[beg];
        float asv = as2[s0];
        ushort4 hv = *(const ushort4*)&h2b[(size_t)s0 * DD + lane * 4];
        for (int j = beg; j < end; ++j) {
            float asn = 0.f;
            ushort4 hn = make_ushort4(0, 0, 0, 0);
            if (j + 1 < end) {
                int sn = elist[j + 1];
                asn = as2[sn];
                hn = *(const ushort4*)&h2b[(size_t)sn * DD + lane * 4];
            }
            float v = lrelu(asv + adn);
            if (v > m) {
                float sc = __expf(m - v);
                den *= sc;
                acc.x *= sc; acc.y *= sc; acc.z *= sc; acc.w *= sc;
                m = v;
            }
            float ex = __expf(v - m);
            den += ex;
            acc.x = fmaf(ex, bf2f(hv.x), acc.x);
            acc.y = fmaf(ex, bf2f(hv.y), acc.y);
            acc.z = fmaf(ex, bf2f(hv.z), acc.z);
            acc.w = fmaf(ex, bf2f(hv.w), acc.w);
            if (j + 1 < end) { asv = asn; hv = hn; }
        }
    }
    float inv = 1.f / (den + 1e-16f);
    float4 bv = *(const float4*)&b2[lane * 4];
    ushort4 o;
    o.x = f2bf(eluf(acc.x * inv + bv.x));
    o.y = f2bf(eluf(acc.y * inv + bv.y));
    o.z = f2bf(eluf(acc.z * inv + bv.z));
    o.w = f2bf(eluf(acc.w * inv + bv.w));
    *(ushort4*)&x2b[(size_t)n * DD + lane * 4] = o;
}

// ---- fused pooling + FC: block g pools its node range, then out row g -------
__global__ __launch_bounds__(128) void pool_final_kernel(const int* __restrict__ gptr,
                                                         const unsigned short* __restrict__ x2b,
                                                         const float* __restrict__ Wfc,
                                                         const float* __restrict__ bfc,
                                                         float* __restrict__ out) {
    __shared__ float pl[DD];
    int g = blockIdx.x;
    int c = threadIdx.x;          // 128 channels
    int beg = gptr[g], end = gptr[g + 1];
    float v = -INFINITY;
    for (int n = beg; n < end; ++n)
        v = fmaxf(v, bf2f(x2b[(size_t)n * DD + c]));
    if (beg == end) v = 0.f;      // empty graph -> 0 (isfinite guard)
    pl[c] = v;
    __syncthreads();
    float acc = bfc[c];
#pragma unroll 8
    for (int k = 0; k < DD; ++k)
        acc = fmaf(pl[k], Wfc[k * DD + c], acc);
    out[(size_t)g * DD + c] = acc > 0.f ? acc : 0.f;
}

extern "C" void kernel_launch(void* const* d_in, const int* in_sizes, int n_in,
                              void* d_out, int out_size, void* d_ws, size_t ws_size,
                              hipStream_t stream) {
    const float* x      = (const float*)d_in[0];
    const int*   ei     = (const int*)d_in[1];
    const int*   batch  = (const int*)d_in[3];
    const float* W1     = (const float*)d_in[4];
    const float* a_src1 = (const float*)d_in[5];
    const float* a_dst1 = (const float*)d_in[6];
    const float* b1     = (const float*)d_in[7];
    const float* W2     = (const float*)d_in[8];
    const float* a_src2 = (const float*)d_in[9];
    const float* a_dst2 = (const float*)d_in[10];
    const float* b2     = (const float*)d_in[11];
    const float* Wfc    = (const float*)d_in[12];
    const float* bfc    = (const float*)d_in[13];
    float* out = (float*)d_out;

    // workspace layout — ~90 MB total
    float* wsf    = (float*)d_ws;
    float* as1    = wsf;                                   // NN*H1
    float* ad1    = as1 + (size_t)NN * H1;                 // NN*H1
    float* as2    = ad1 + (size_t)NN * H1;                 // NN
    float* ad2    = as2 + NN;                              // NN
    int*   deg    = (int*)(ad2 + NN);                      // NN
    int*   rowptr = deg + NN;                              // NN+1
    int*   cursor = rowptr + NN + 1;                       // NN
    int*   elist  = cursor + NN;                           // ET
    int*   gptr   = elist + ET;                            // NG+1
    int*   bsum   = gptr + NG + 1;                         // 256
    size_t off = (size_t)((char*)(bsum + 256) - (char*)d_ws);
    off = (off + 15) & ~(size_t)15;
    unsigned short* W2p   = (unsigned short*)((char*)d_ws + off);    // KK*DD bf16
    unsigned short* W1pT  = W2p + (size_t)KK * DD;                   // 40960 bf16
    unsigned short* xaggb = W1pT + 40960;                            // NN*H1*32 bf16
    unsigned short* h2b   = xaggb + (size_t)NN * H1 * 32;            // NN*DD bf16
    unsigned short* x2b   = h2b + (size_t)NN * DD;                   // NN*DD bf16

    hipMemsetAsync(deg, 0, (size_t)NN * sizeof(int), stream);
    setup_kernel     <<<1312 + (ET + 255) / 256, 256, 0, stream>>>(
                        W1, W2, a_src1, a_dst1, x, batch, ei,
                        W2p, W1pT, as1, ad1, deg, gptr);
    scan1_kernel     <<<256, 256, 0, stream>>>(deg, bsum);
    scan2_kernel     <<<1, 256, 0, stream>>>(bsum, rowptr);
    scan3_kernel     <<<256, 256, 0, stream>>>(deg, bsum, rowptr, cursor);
    scatter_kernel   <<<(ET + 255) / 256, 256, 0, stream>>>(ei, cursor, elist);
    agg1_kernel      <<<(NN * H1 + 255) / 256, 256, 0, stream>>>(rowptr, elist, x, as1, ad1, xaggb);
    h2_gemm          <<<NN / 128, 512, 0, stream>>>(xaggb, W1pT, b1, W2p, a_src2, a_dst2,
                                                    h2b, as2, ad2);
    agg2_kernel      <<<(NN * 32) / 256, 256, 0, stream>>>(rowptr, elist, h2b, as2, ad2, b2, x2b);
    pool_final_kernel<<<NG, 128, 0, stream>>>(gptr, x2b, Wfc, bfc, out);
}

// Round 19
// 155.544 us; speedup vs baseline: 1.6061x; 1.0531x over previous
//
#include <hip/hip_runtime.h>
#include <hip/hip_bf16.h>
#include <math.h>

#define NN 65536          // nodes
#define NE 196608         // edges (without self loops)
#define ET (NE + NN)      // edges + self loops = 262144
#define NG 2048           // graphs
#define FIN 9
#define DD 128
#define H1 10
#define KK (H1 * DD)      // 1280
#define LRS 0.2f
#define XSB 36            // xsb row stride (ushorts): 72B rows

typedef __attribute__((ext_vector_type(8))) short short8v;
typedef __attribute__((ext_vector_type(4))) float f32x4;

__device__ __forceinline__ float lrelu(float v) { return v >= 0.f ? v : LRS * v; }
__device__ __forceinline__ float eluf(float v)  { return v > 0.f ? v : expm1f(v); }

// float -> bf16 round-to-nearest-even (3 int ops, no libcall)
__device__ __forceinline__ unsigned short f2bf(float f) {
    unsigned int u = __float_as_uint(f);
    u += 0x7FFFu + ((u >> 16) & 1u);
    return (unsigned short)(u >> 16);
}
__device__ __forceinline__ float bf2f(unsigned short s) {
    return __uint_as_float((unsigned int)s << 16);
}

// ---- setup: packW2 | alpha1+prep | gptr | packW1pT | count (deg pre-zeroed
// ---- by hipMemsetAsync). All branches independent. -------------------------
__global__ __launch_bounds__(256) void setup_kernel(
        const float* __restrict__ W1, const float* __restrict__ W2,
        const float* __restrict__ a_src1, const float* __restrict__ a_dst1,
        const float* __restrict__ x, const int* __restrict__ batch,
        const int* __restrict__ ei,
        unsigned short* __restrict__ W2p, unsigned short* __restrict__ W1pT,
        float* __restrict__ as1, float* __restrict__ ad1,
        int* __restrict__ deg, int* __restrict__ gptr) {
    __shared__ float ws_s[FIN * H1], wd_s[FIN * H1];
    const int b = blockIdx.x;
    const int t = threadIdx.x;
    if (b < 640) {
        // W2 (1280x128 fp32) -> bf16 B-fragment layout
        int idx = b * 256 + t;
        int r  = idx & 7;
        int l  = (idx >> 3) & 63;
        int nt = (idx >> 9) & 7;
        int kt = idx >> 12;
        int k = kt * 32 + ((l >> 4) << 3) + r;
        int n = nt * 16 + (l & 15);
        W2p[idx] = f2bf(W2[(size_t)k * DD + n]);
    } else if (b < 896) {
        if (t < FIN * H1) {
            int f = t / H1, h = t - f * H1;
            float s = 0.f, d = 0.f;
            for (int c = 0; c < DD; ++c) {
                float w = W1[f * KK + h * DD + c];
                s = fmaf(w, a_src1[h * DD + c], s);
                d = fmaf(w, a_dst1[h * DD + c], d);
            }
            ws_s[t] = s;
            wd_s[t] = d;
        }
        __syncthreads();
        int n = (b - 640) * 256 + t;
        float xv[FIN];
#pragma unroll
        for (int f = 0; f < FIN; ++f) xv[f] = x[(size_t)n * FIN + f];
#pragma unroll
        for (int h = 0; h < H1; ++h) {
            float s = 0.f, d = 0.f;
#pragma unroll
            for (int f = 0; f < FIN; ++f) {
                s = fmaf(xv[f], ws_s[f * H1 + h], s);
                d = fmaf(xv[f], wd_s[f * H1 + h], d);
            }
            as1[n * H1 + h] = s;
            ad1[n * H1 + h] = d;
        }
    } else if (b < 1152) {
        int n = (b - 896) * 256 + t;
        int bn = batch[n];
        int bp = (n == 0) ? -1 : batch[n - 1];
        for (int g = bp + 1; g <= bn; ++g) gptr[g] = n;
        if (n == NN - 1) {
            for (int g = bn + 1; g <= NG; ++g) gptr[g] = NN;
        }
    } else if (b < 1312) {
        // W1^T -> bf16 A-fragment layout for the expansion MFMA (K=9 pad 32)
        int idx = (b - 1152) * 256 + t;            // 40960 total
        int r  = idx & 7;
        int l  = (idx >> 3) & 63;
        int mt = (idx >> 9) & 7;
        int h  = idx >> 12;
        int f  = ((l >> 4) << 3) + r;
        int c  = mt * 16 + (l & 15);
        W1pT[idx] = (f < FIN) ? f2bf(W1[(size_t)f * KK + h * DD + c]) : (unsigned short)0;
    } else {
        // degree count (deg zeroed by async memset before this kernel)
        int e = (b - 1312) * 256 + t;
        if (e < ET) {
            int d = (e < NE) ? ei[NE + e] : e - NE;
            atomicAdd(&deg[d], 1);
        }
    }
}

// ---- CSR build: coalesced scan (2 kernels) / scatter -------------------------
__global__ __launch_bounds__(256) void scan1_kernel(const int* __restrict__ deg,
                                                    int* __restrict__ bsum) {
    __shared__ int sc[256];
    int t = threadIdx.x, b = blockIdx.x;
    sc[t] = deg[b * 256 + t];
    __syncthreads();
    for (int off = 128; off > 0; off >>= 1) {
        if (t < off) sc[t] += sc[t + off];
        __syncthreads();
    }
    if (t == 0) bsum[b] = sc[0];
}

// fused scan2+scan3: every block redundantly prefix-sums the 256 block sums
// (1 KB, L2-hot), then does its local exclusive scan + offset.
__global__ __launch_bounds__(256) void scan23_kernel(const int* __restrict__ deg,
                                                     const int* __restrict__ bsum,
                                                     int* __restrict__ rowptr,
                                                     int* __restrict__ cursor) {
    __shared__ int sb[256], sc[256];
    int t = threadIdx.x, b = blockIdx.x;
    sb[t] = bsum[t];
    int i = b * 256 + t;
    int v = deg[i];
    sc[t] = v;
    __syncthreads();
    for (int off = 1; off < 256; off <<= 1) {
        int ub = (t >= off) ? sb[t - off] : 0;
        int uc = (t >= off) ? sc[t - off] : 0;
        __syncthreads();
        sb[t] += ub;
        sc[t] += uc;
        __syncthreads();
    }
    int base = (b == 0) ? 0 : sb[b - 1];
    int r = base + sc[t] - v;
    rowptr[i] = r;
    cursor[i] = r;
    if (b == 255 && t == 255) rowptr[NN] = sb[255];
}

__global__ void scatter_kernel(const int* __restrict__ ei, int* __restrict__ cursor,
                               int* __restrict__ elist) {
    int e = blockIdx.x * 256 + threadIdx.x;
    if (e >= ET) return;
    int s, d;
    if (e < NE) { s = ei[e]; d = ei[NE + e]; } else { s = d = e - NE; }
    int pos = atomicAdd(&cursor[d], 1);
    elist[pos] = s;
}

// ---- layer-1 aggregation: per-(node,head), online softmax, DEPTH-2 PIPELINE --
// Index kept 2 iterations ahead, data 1 ahead: breaks the idx->data serial
// dependency. Every node has >=1 edge (self-loop).
__global__ void agg1_kernel(const int* __restrict__ rowptr, const int* __restrict__ elist,
                            const float* __restrict__ x,
                            const float* __restrict__ as1, const float* __restrict__ ad1,
                            unsigned short* __restrict__ xaggb) {
    int idx = blockIdx.x * 256 + threadIdx.x;     // NN*H1
    if (idx >= NN * H1) return;
    int d = idx / H1, h = idx - d * H1;
    int beg = rowptr[d], end = rowptr[d + 1];
    float adh = ad1[d * H1 + h];
    float m = -INFINITY, den = 0.f;
    float xa[FIN] = {};
    {
        int s0 = elist[beg];                               // idx j
        int sB = (beg + 1 < end) ? elist[beg + 1] : s0;    // idx j+1 (resident)
        float asv = as1[s0 * H1 + h];                      // data j
        float xs[FIN];
#pragma unroll
        for (int f = 0; f < FIN; ++f) xs[f] = x[(size_t)s0 * FIN + f];
        for (int j = beg; j < end; ++j) {
            int sC = (j + 2 < end) ? elist[j + 2] : sB;    // issue idx j+2
            float asn = 0.f, xn[FIN];
            if (j + 1 < end) {                             // data j+1 (idx resident)
                asn = as1[sB * H1 + h];
#pragma unroll
                for (int f = 0; f < FIN; ++f) xn[f] = x[(size_t)sB * FIN + f];
            }
            float v = lrelu(asv + adh);
            if (v > m) {
                float sc = __expf(m - v);
                den *= sc;
#pragma unroll
                for (int f = 0; f < FIN; ++f) xa[f] *= sc;
                m = v;
            }
            float ex = __expf(v - m);
            den += ex;
#pragma unroll
            for (int f = 0; f < FIN; ++f) xa[f] = fmaf(ex, xs[f], xa[f]);
            if (j + 1 < end) {
                asv = asn;
#pragma unroll
                for (int f = 0; f < FIN; ++f) xs[f] = xn[f];
            }
            sB = sC;
        }
    }
    float inv = 1.f / (den + 1e-16f);
    unsigned int w[16];
#pragma unroll
    for (int i = 0; i < 16; ++i) w[i] = 0u;
#pragma unroll
    for (int f = 0; f < FIN; ++f) {
        unsigned int bv = f2bf(xa[f] * inv);
        w[f >> 1] |= bv << ((f & 1) * 16);
    }
    uint4* dst = (uint4*)&xaggb[(size_t)idx * 32];
    dst[0] = make_uint4(w[0], w[1], w[2], w[3]);
    dst[1] = make_uint4(w[4], w[5], w[6], w[7]);
    dst[2] = make_uint4(w[8], w[9], w[10], w[11]);
    dst[3] = make_uint4(w[12], w[13], w[14], w[15]);
}

// ---- h2 = elu(xagg@W1 + b1) @ W2, BOTH matmuls on MFMA + alpha2 epilogue ----
// v9 (measured best): Xs split into two 64-col halves (v6 swizzle);
// xsb double-buffered; bf16 h2 written via LDS re-stage, coalesced uint4.
__global__ __launch_bounds__(512, 4) void h2_gemm(
        const unsigned short* __restrict__ xaggb,
        const unsigned short* __restrict__ W1pT,
        const float* __restrict__ b1,
        const unsigned short* __restrict__ W2p,
        const float* __restrict__ a_src2, const float* __restrict__ a_dst2,
        unsigned short* __restrict__ h2b, float* __restrict__ as2,
        float* __restrict__ ad2) {
    __shared__ unsigned short Xs0[128 * 64];          // 16 KB, v6 swizzle
    __shared__ unsigned short Xs1[128 * 64];          // 16 KB
    __shared__ unsigned short xsb[2][128 * XSB];      // 2 x 9 KB
    __shared__ float as_s[128], ad_s[128];
    const int t = threadIdx.x;
    const int n0 = blockIdx.x * 128;
    const int lane = t & 63;
    const int wvu = __builtin_amdgcn_readfirstlane(t >> 6);   // 0..7
    const int rh = wvu & 1, cq = wvu >> 1;                    // main-GEMM roles
    const int rlo = lane & 15, khi = lane >> 4;
    const int srow = t >> 2, sseg = t & 3;                    // xsb stage roles

    if (t < 128) { as_s[t] = 0.f; ad_s[t] = 0.f; }

    f32x4 acc[4][2];
#pragma unroll
    for (int mt = 0; mt < 4; ++mt)
#pragma unroll
        for (int ntl = 0; ntl < 2; ++ntl)
#pragma unroll
            for (int q = 0; q < 4; ++q) acc[mt][ntl][q] = 0.f;

    // prologue: stage head 0's xagg slice
    *(uint4*)&xsb[0][srow * XSB + sseg * 8] =
        *(const uint4*)&xaggb[((size_t)(n0 + srow) * H1 + 0) * 32 + sseg * 8];

    for (int h = 0; h < H1; ++h) {
        const int cur = h & 1;
        __syncthreads();                  // xsb[cur] staged; prev Xs reads done

        // expansion: wave owns c-tile wvu (16 cols of x1 within this head)
        short8v a1 = *(const short8v*)&W1pT[(((size_t)h * 8 + wvu) * 64 + lane) * 8];
        float4 bv4 = *(const float4*)&b1[h * DD + wvu * 16 + khi * 4];
        unsigned short* XsW = (wvu >> 2) ? Xs1 : Xs0;          // write half
        const int gw7 = (wvu * 2 + (khi >> 1)) & 7;            // granule in half
#pragma unroll
        for (int nh = 0; nh < 2; ++nh) {
            f32x4 acc2[4];
#pragma unroll
            for (int j = 0; j < 4; ++j) {
                int nt = nh * 4 + j;
                short8v bfrag = *(const short8v*)&xsb[cur][(nt * 16 + rlo) * XSB + khi * 8];
                f32x4 zz = {0.f, 0.f, 0.f, 0.f};
                acc2[j] = __builtin_amdgcn_mfma_f32_16x16x32_bf16(a1, bfrag, zz, 0, 0, 0);
            }
#pragma unroll
            for (int j = 0; j < 4; ++j) {
                int nt = nh * 4 + j;
                float z0 = acc2[j][0] + bv4.x;
                float z1 = acc2[j][1] + bv4.y;
                float z2 = acc2[j][2] + bv4.z;
                float z3 = acc2[j][3] + bv4.w;
                z0 = z0 > 0.f ? z0 : __expf(z0) - 1.f;
                z1 = z1 > 0.f ? z1 : __expf(z1) - 1.f;
                z2 = z2 > 0.f ? z2 : __expf(z2) - 1.f;
                z3 = z3 > 0.f ? z3 : __expf(z3) - 1.f;
                unsigned int lo = (unsigned int)f2bf(z0) | ((unsigned int)f2bf(z1) << 16);
                unsigned int hi = (unsigned int)f2bf(z2) | ((unsigned int)f2bf(z3) << 16);
                int rown = nt * 16 + rlo;                      // node row
                unsigned offu = rown * 64 + (((gw7 ^ (rown & 7)) << 3) | ((khi & 1) << 2));
                *(uint2*)&XsW[offu] = make_uint2(lo, hi);
            }
        }
        __syncthreads();                  // Xs visible

        // stage next head's xagg slice into the other xsb buffer (overlaps GEMM)
        if (h + 1 < H1) {
            *(uint4*)&xsb[cur ^ 1][srow * XSB + sseg * 8] =
                *(const uint4*)&xaggb[((size_t)(n0 + srow) * H1 + (h + 1)) * 32 + sseg * 8];
        }

        // main GEMM: this head's K=128 (4 sub-K of 32; ks<2 -> Xs0, ks>=2 -> Xs1)
#pragma unroll
        for (int ks = 0; ks < 4; ++ks) {
            const int ktabs = h * 4 + ks;
            const unsigned short* XsR = (ks >> 1) ? Xs1 : Xs0;
            const int g7 = (ks & 1) * 4 + khi;                 // granule in half
            short8v bfr[2];
#pragma unroll
            for (int ntl = 0; ntl < 2; ++ntl) {
                const int nt = cq * 2 + ntl;
                bfr[ntl] = *(const short8v*)&W2p[(((size_t)ktabs * 8 + nt) * 64 + lane) * 8];
            }
#pragma unroll
            for (int mt = 0; mt < 4; ++mt) {
                const int row2 = rh * 64 + mt * 16 + rlo;
                unsigned offu = row2 * 64 + ((g7 ^ (row2 & 7)) << 3);
                short8v af = *(const short8v*)&XsR[offu];
                acc[mt][0] = __builtin_amdgcn_mfma_f32_16x16x32_bf16(af, bfr[0], acc[mt][0], 0, 0, 0);
                acc[mt][1] = __builtin_amdgcn_mfma_f32_16x16x32_bf16(af, bfr[1], acc[mt][1], 0, 0, 0);
            }
        }
    }

    // epilogue: stage acc tile as bf16 into dead Xs buffers, then coalesced copy
    __syncthreads();                      // last head's Xs reads done
#pragma unroll
    for (int mt = 0; mt < 4; ++mt)
#pragma unroll
        for (int ntl = 0; ntl < 2; ++ntl) {
            int col = cq * 32 + ntl * 16 + rlo;
            unsigned short* Xw = (col < 64) ? Xs0 : Xs1;
            int c64 = col & 63;
#pragma unroll
            for (int q = 0; q < 4; ++q) {
                int row = rh * 64 + mt * 16 + khi * 4 + q;
                Xw[row * 64 + c64] = f2bf(acc[mt][ntl][q]);
            }
        }
    __syncthreads();
#pragma unroll
    for (int i = 0; i < 4; ++i) {
        int j = i * 512 + t;              // uint4 index over the 128x128 tile
        int row = j >> 4;                 // 16 uint4 per 128-col row
        int c8 = (j & 15) * 8;
        const unsigned short* S = (c8 < 64) ? Xs0 : Xs1;
        uint4 v = *(const uint4*)&S[row * 64 + (c8 & 63)];
        *(uint4*)&h2b[(size_t)(n0 + row) * DD + c8] = v;
    }

    // fused alpha2 from fp32 accumulators
    float sp[16], dp[16];
#pragma unroll
    for (int mt = 0; mt < 4; ++mt)
#pragma unroll
        for (int q = 0; q < 4; ++q) {
            float a = 0.f, b = 0.f;
#pragma unroll
            for (int ntl = 0; ntl < 2; ++ntl) {
                int col = cq * 32 + ntl * 16 + rlo;
                float v = acc[mt][ntl][q];
                a = fmaf(v, a_src2[col], a);
                b = fmaf(v, a_dst2[col], b);
            }
            sp[mt * 4 + q] = a;
            dp[mt * 4 + q] = b;
        }
#pragma unroll
    for (int off = 1; off < 16; off <<= 1) {
#pragma unroll
        for (int i = 0; i < 16; ++i) {
            sp[i] += __shfl_xor(sp[i], off);
            dp[i] += __shfl_xor(dp[i], off);
        }
    }
    if (rlo == 0) {
#pragma unroll
        for (int mt = 0; mt < 4; ++mt)
#pragma unroll
            for (int q = 0; q < 4; ++q) {
                atomicAdd(&as_s[rh * 64 + mt * 16 + khi * 4 + q], sp[mt * 4 + q]);
                atomicAdd(&ad_s[rh * 64 + mt * 16 + khi * 4 + q], dp[mt * 4 + q]);
            }
    }
    __syncthreads();
    if (t < 128) {
        as2[n0 + t] = as_s[t];
        ad2[n0 + t] = ad_s[t];
    }
}

// ---- layer-2 aggregation (online softmax, bf16 h2), DEPTH-2 PIPELINE --------
__global__ void agg2_kernel(const int* __restrict__ rowptr, const int* __restrict__ elist,
                            const unsigned short* __restrict__ h2b,
                            const float* __restrict__ as2, const float* __restrict__ ad2,
                            const float* __restrict__ b2, unsigned short* __restrict__ x2b) {
    int gid = blockIdx.x * 256 + threadIdx.x;
    int n = gid >> 5, lane = gid & 31;
    if (n >= NN) return;
    int beg = rowptr[n], end = rowptr[n + 1];
    float adn = ad2[n];
    float m = -INFINITY, den = 0.f;
    float4 acc = make_float4(0.f, 0.f, 0.f, 0.f);
    {
        int s0 = elist[beg];                               // idx j
        int sB = (beg + 1 < end) ? elist[beg + 1] : s0;    // idx j+1 (resident)
        float asv = as2[s0];
        ushort4 hv = *(const ushort4*)&h2b[(size_t)s0 * DD + lane * 4];
        for (int j = beg; j < end; ++j) {
            int sC = (j + 2 < end) ? elist[j + 2] : sB;    // issue idx j+2
            float asn = 0.f;
            ushort4 hn = make_ushort4(0, 0, 0, 0);
            if (j + 1 < end) {                             // data j+1 (idx resident)
                asn = as2[sB];
                hn = *(const ushort4*)&h2b[(size_t)sB * DD + lane * 4];
            }
            float v = lrelu(asv + adn);
            if (v > m) {
                float sc = __expf(m - v);
                den *= sc;
                acc.x *= sc; acc.y *= sc; acc.z *= sc; acc.w *= sc;
                m = v;
            }
            float ex = __expf(v - m);
            den += ex;
            acc.x = fmaf(ex, bf2f(hv.x), acc.x);
            acc.y = fmaf(ex, bf2f(hv.y), acc.y);
            acc.z = fmaf(ex, bf2f(hv.z), acc.z);
            acc.w = fmaf(ex, bf2f(hv.w), acc.w);
            if (j + 1 < end) { asv = asn; hv = hn; }
            sB = sC;
        }
    }
    float inv = 1.f / (den + 1e-16f);
    float4 bv = *(const float4*)&b2[lane * 4];
    ushort4 o;
    o.x = f2bf(eluf(acc.x * inv + bv.x));
    o.y = f2bf(eluf(acc.y * inv + bv.y));
    o.z = f2bf(eluf(acc.z * inv + bv.z));
    o.w = f2bf(eluf(acc.w * inv + bv.w));
    *(ushort4*)&x2b[(size_t)n * DD + lane * 4] = o;
}

// ---- fused pooling + FC: block g pools its node range, then out row g -------
__global__ __launch_bounds__(128) void pool_final_kernel(const int* __restrict__ gptr,
                                                         const unsigned short* __restrict__ x2b,
                                                         const float* __restrict__ Wfc,
                                                         const float* __restrict__ bfc,
                                                         float* __restrict__ out) {
    __shared__ float pl[DD];
    int g = blockIdx.x;
    int c = threadIdx.x;          // 128 channels
    int beg = gptr[g], end = gptr[g + 1];
    float v = -INFINITY;
    for (int n = beg; n < end; ++n)
        v = fmaxf(v, bf2f(x2b[(size_t)n * DD + c]));
    if (beg == end) v = 0.f;      // empty graph -> 0 (isfinite guard)
    pl[c] = v;
    __syncthreads();
    float acc = bfc[c];
#pragma unroll 8
    for (int k = 0; k < DD; ++k)
        acc = fmaf(pl[k], Wfc[k * DD + c], acc);
    out[(size_t)g * DD + c] = acc > 0.f ? acc : 0.f;
}

extern "C" void kernel_launch(void* const* d_in, const int* in_sizes, int n_in,
                              void* d_out, int out_size, void* d_ws, size_t ws_size,
                              hipStream_t stream) {
    const float* x      = (const float*)d_in[0];
    const int*   ei     = (const int*)d_in[1];
    const int*   batch  = (const int*)d_in[3];
    const float* W1     = (const float*)d_in[4];
    const float* a_src1 = (const float*)d_in[5];
    const float* a_dst1 = (const float*)d_in[6];
    const float* b1     = (const float*)d_in[7];
    const float* W2     = (const float*)d_in[8];
    const float* a_src2 = (const float*)d_in[9];
    const float* a_dst2 = (const float*)d_in[10];
    const float* b2     = (const float*)d_in[11];
    const float* Wfc    = (const float*)d_in[12];
    const float* bfc    = (const float*)d_in[13];
    float* out = (float*)d_out;

    // workspace layout — ~90 MB total
    float* wsf    = (float*)d_ws;
    float* as1    = wsf;                                   // NN*H1
    float* ad1    = as1 + (size_t)NN * H1;                 // NN*H1
    float* as2    = ad1 + (size_t)NN * H1;                 // NN
    float* ad2    = as2 + NN;                              // NN
    int*   deg    = (int*)(ad2 + NN);                      // NN
    int*   rowptr = deg + NN;                              // NN+1
    int*   cursor = rowptr + NN + 1;                       // NN
    int*   elist  = cursor + NN;                           // ET
    int*   gptr   = elist + ET;                            // NG+1
    int*   bsum   = gptr + NG + 1;                         // 256
    size_t off = (size_t)((char*)(bsum + 256) - (char*)d_ws);
    off = (off + 15) & ~(size_t)15;
    unsigned short* W2p   = (unsigned short*)((char*)d_ws + off);    // KK*DD bf16
    unsigned short* W1pT  = W2p + (size_t)KK * DD;                   // 40960 bf16
    unsigned short* xaggb = W1pT + 40960;                            // NN*H1*32 bf16
    unsigned short* h2b   = xaggb + (size_t)NN * H1 * 32;            // NN*DD bf16
    unsigned short* x2b   = h2b + (size_t)NN * DD;                   // NN*DD bf16

    hipMemsetAsync(deg, 0, (size_t)NN * sizeof(int), stream);
    setup_kernel     <<<1312 + (ET + 255) / 256, 256, 0, stream>>>(
                        W1, W2, a_src1, a_dst1, x, batch, ei,
                        W2p, W1pT, as1, ad1, deg, gptr);
    scan1_kernel     <<<256, 256, 0, stream>>>(deg, bsum);
    scan23_kernel    <<<256, 256, 0, stream>>>(deg, bsum, rowptr, cursor);
    scatter_kernel   <<<(ET + 255) / 256, 256, 0, stream>>>(ei, cursor, elist);
    agg1_kernel      <<<(NN * H1 + 255) / 256, 256, 0, stream>>>(rowptr, elist, x, as1, ad1, xaggb);
    h2_gemm          <<<NN / 128, 512, 0, stream>>>(xaggb, W1pT, b1, W2p, a_src2, a_dst2,
                                                    h2b, as2, ad2);
    agg2_kernel      <<<(NN * 32) / 256, 256, 0, stream>>>(rowptr, elist, h2b, as2, ad2, b2, x2b);
    pool_final_kernel<<<NG, 128, 0, stream>>>(gptr, x2b, Wfc, bfc, out);
}